// Round 9
// baseline (507.545 us; speedup 1.0000x reference)
//
#include <hip/hip_runtime.h>
#include <hip/hip_bf16.h>
#include <stdint.h>

#define NTOT  300000
#define NNODE 50000
#define RPD   16
#define NREL  50
#define EMB   16
#define NC    10
#define EPSF  1e-6f
#define SG    49   // scan blocks per side: 49*1024 >= 50000

typedef const __hip_bfloat16* bf16p;

__device__ __forceinline__ float b2f(__hip_bfloat16 x){ return __bfloat162float(x); }

__device__ __forceinline__ void unpack2(unsigned u, float& a, float& b){
  a = __uint_as_float(u << 16);
  b = __uint_as_float(u & 0xffff0000u);
}

// fp32 -> bf16 bits, round-to-nearest-even
__device__ __forceinline__ unsigned bfb(float x){
  unsigned u = __float_as_uint(x);
  return (u + 0x7FFFu + ((u >> 16) & 1u)) >> 16;
}

__device__ __forceinline__ float ldf(const void* p, int i, int bf){
  return bf ? b2f(((bf16p)p)[i]) : ((const float*)p)[i];
}

// ---- dtype detection: fp32 one-hot rows contain ONLY words 0x0 / 0x3F800000.
__global__ void k_detect(const unsigned* nraw, int* flag){
  __shared__ int bad;
  if(threadIdx.x == 0) bad = 0;
  __syncthreads();
  for(int i = threadIdx.x; i < 4096; i += 1024){
    unsigned w = nraw[i];
    if(w != 0u && w != 0x3F800000u) bad = 1;
  }
  __syncthreads();
  if(threadIdx.x == 0) *flag = bad;   // 1 => bf16 mode, 0 => fp32 mode
}

__global__ void k_zero(float* p, long n){
  long i = (long)blockIdx.x*blockDim.x + threadIdx.x;
  long stride = (long)gridDim.x*blockDim.x;
  for(; i < n; i += stride) p[i] = 0.f;
}

// softmax tables: T1/T2[rel][r] = softmax_r(Wl[rel][r] + bl[r])
__global__ void k_tables(const void* Wl1, const void* bl1, const void* Wl2, const void* bl2,
                         float* T1, float* T2, const int* flag){
  int bf = *flag;
  int i = threadIdx.x;
  const void* W = nullptr; const void* bl = nullptr; float* T = nullptr; int row = -1;
  if(i < NREL){ W = Wl1; bl = bl1; T = T1; row = i; }
  else if(i >= 64 && i < 64 + NREL){ W = Wl2; bl = bl2; T = T2; row = i - 64; }
  if(row >= 0){
    float v[RPD]; float m = -1e30f;
    for(int r = 0; r < RPD; r++){
      v[r] = ldf(W, row*RPD + r, bf) + ldf(bl, r, bf);
      m = fmaxf(m, v[r]);
    }
    float s = 0.f;
    for(int r = 0; r < RPD; r++){ v[r] = __expf(v[r] - m); s += v[r]; }
    float inv = 1.f / s;
    for(int r = 0; r < RPD; r++) T[row*RPD + r] = v[r] * inv;
  }
}

// argmax relation per edge + degree histograms for both CSRs
__global__ __launch_bounds__(256) void k_argmax(const void* nhots, const int* srow, const int* ocol,
    int* p, int* cnt_s, int* cnt_o, const int* flag){
  int bf = *flag;
  int t = blockIdx.x*256 + threadIdx.x;
  if(t >= NTOT) return;
  int pt = 0; float best = -1e30f;
  if(bf){
    const unsigned* row = (const unsigned*)nhots + (size_t)t*(NREL/2);
    for(int k = 0; k < NREL/2; k++){
      float a, b; unpack2(row[k], a, b);
      if(a > best){ best = a; pt = 2*k;   }
      if(b > best){ best = b; pt = 2*k+1; }
    }
  } else {
    const uint2* row = (const uint2*)((const float*)nhots + (size_t)t*NREL);
    for(int k = 0; k < NREL/2; k++){
      uint2 u = row[k];
      float a = __uint_as_float(u.x), b = __uint_as_float(u.y);
      if(a > best){ best = a; pt = 2*k;   }
      if(b > best){ best = b; pt = 2*k+1; }
    }
  }
  p[t] = pt;
  atomicAdd(&cnt_s[srow[t]], 1);
  atomicAdd(&cnt_o[ocol[t]], 1);
}

// ---- 3-phase scan
__global__ __launch_bounds__(1024) void k_scanA(const int* cnt_s, const int* cnt_o,
    int* start_s, int* start_o, int* bsum){
  int G = gridDim.x >> 1;
  bool oside = blockIdx.x >= G;
  int b = oside ? blockIdx.x - G : blockIdx.x;
  const int* cnt = oside ? cnt_o : cnt_s;
  int* start = oside ? start_o : start_s;
  __shared__ int sh[1024];
  int tid = threadIdx.x;
  int idx = b*1024 + tid;
  int v = (idx < NNODE) ? cnt[idx] : 0;
  sh[tid] = v;
  __syncthreads();
  for(int off = 1; off < 1024; off <<= 1){
    int n = (tid >= off) ? sh[tid - off] : 0;
    __syncthreads();
    sh[tid] += n;
    __syncthreads();
  }
  if(idx < NNODE) start[idx] = sh[tid] - v;   // block-local exclusive
  if(tid == 1023) bsum[(oside ? G : 0) + b] = sh[1023];
}

__global__ void k_scanB(int* bsum, int* start_s, int* start_o){
  int tid = threadIdx.x;          // 128 = 2 waves; wave0 = s-side, wave1 = o-side
  bool oside = tid >= 64;
  int lane = tid & 63;
  int base = oside ? SG : 0;
  int v = (lane < SG) ? bsum[base + lane] : 0;
  int orig = v;
  for(int off = 1; off < 64; off <<= 1){
    int n = __shfl_up(v, off);
    if(lane >= off) v += n;
  }
  if(lane < SG) bsum[base + lane] = v - orig;  // exclusive block offset
  if(lane == 63){
    if(oside) start_o[NNODE] = v; else start_s[NNODE] = v;
  }
}

__global__ __launch_bounds__(1024) void k_scanC(int* start_s, int* start_o,
    int* cursor_s, int* cursor_o, const int* bsum){
  int G = gridDim.x >> 1;
  bool oside = blockIdx.x >= G;
  int b = oside ? blockIdx.x - G : blockIdx.x;
  int idx = b*1024 + threadIdx.x;
  if(idx >= NNODE) return;
  int ofs = bsum[(oside ? G : 0) + b];
  int* start  = oside ? start_o  : start_s;
  int* cursor = oside ? cursor_o : cursor_s;
  int v = start[idx] + ofs;
  start[idx] = v;
  cursor[idx] = v;
}

// fill both CSRs with PACKED edge records (SoA for the o-side):
//   rec_s[pos]   = o | p<<16    (o < 2^16, p < 64)
//   rec_op[posO] = pos_s | p<<19 (pos_s < 2^19),  rec_oo[posO] = o
__global__ void k_fill(const int* srow, const int* ocol, const int* p,
                       int* cursor_s, int* cursor_o, int* rec_s, int* rec_op, int* rec_oo){
  int t = blockIdx.x*256 + threadIdx.x;
  if(t >= NTOT) return;
  int s = srow[t], o = ocol[t], pt = p[t];
  int pos  = atomicAdd(&cursor_s[s], 1);
  int posO = atomicAdd(&cursor_o[o], 1);
  rec_s[pos] = o | (pt << 16);
  rec_op[posO] = pos | (pt << 19);
  rec_oo[posO] = o;
}

// S1[o][r] = sum_{edges of o} T1[p][r]. Wave per node; cooperative rec load +
// shfl broadcast => LDS-only inner loop. r=0 flood partials -> floodSo[64].
__global__ __launch_bounds__(256) void k_S1(const int* start_o, const int* rec_op,
    const float* T1, float* S1, float* floodSo){
  __shared__ float lT[NREL*RPD];
  __shared__ float w0[4];
  int tid = threadIdx.x;
  for(int i = tid; i < NREL*RPD; i += 256) lT[i] = T1[i];
  __syncthreads();
  int wave = tid >> 6, lane = tid & 63;
  int r = lane & 15;
  int node = blockIdx.x*4 + wave;
  float acc = 0.f;
  int e0 = start_o[node], e1 = start_o[node+1];
  for(int base = e0; base < e1; base += 64){
    int k = min(64, e1 - base);
    int rv = (lane < k) ? rec_op[base + lane] : 0;
    for(int i = 0; i < k; i++){
      int pt = ((unsigned)__shfl(rv, i)) >> 19;
      acc += lT[pt*RPD + r];
    }
  }
  if(lane < 16) S1[node*RPD + r] = acc;
  if(lane == 0) w0[wave] = acc;   // r==0 value
  __syncthreads();
  if(tid == 0)
    atomicAdd(&floodSo[blockIdx.x & 63], w0[0]+w0[1]+w0[2]+w0[3]);
}

// icolsum[v] = 1/max(eps, sum_{r=1..15, r|v, v/r<N} S1[v/r][r]); v==0 adds the r=0 flood.
__global__ __launch_bounds__(256) void k_icolsum(const float* S1, const float* floodSo, float* icolsum){
  int stride = gridDim.x*256;
  for(int v = blockIdx.x*256 + threadIdx.x; v < NNODE*RPD; v += stride){
    float acc = 0.f;
    #pragma unroll
    for(int r = 1; r <= 15; r++){
      if(v % (unsigned)r == 0u){
        int s = (unsigned)v / (unsigned)r;
        if(s < NNODE) acc += S1[s*RPD + r];
      }
    }
    if(v == 0){
      float f = 0.f;
      for(int k = 0; k < 64; k++) f += floodSo[k];
      acc += f;
    }
    icolsum[v] = 1.f / fmaxf(acc, EPSF);
  }
}

// layer1, edge x emb-quad parallel, fully coalesced record reads:
// C[psx][q] = sum_r T1[pt][r] * icolsum[o*r] * W1[o*r][q-quad]
__global__ __launch_bounds__(256) void k_hC(const int* rec_op, const int* rec_oo,
    const float* T1, const float* icolsum, const void* W1, float* C, const int* flag){
  __shared__ float lT1[NREL*RPD];
  int bf = *flag;
  int tid = threadIdx.x;
  for(int i = tid; i < NREL*RPD; i += 256) lT1[i] = T1[i];
  __syncthreads();
  int id = blockIdx.x*256 + tid;
  int e = id >> 2, q = id & 3;
  if(e >= NTOT) return;
  int w  = rec_op[e];
  int o  = rec_oo[e];
  int psx = w & 0x7FFFF;
  int pt  = ((unsigned)w) >> 19;
  const float* t1 = lT1 + pt*RPD;
  float4 acc = {0.f,0.f,0.f,0.f};
  #pragma unroll
  for(int r = 0; r < RPD; r++){
    int c = o * r;
    float wgt = t1[r] * icolsum[c];
    float4 f;
    if(bf){
      uint2 u = *((const uint2*)((const char*)W1 + (size_t)c*32) + q);
      unpack2(u.x, f.x, f.y); unpack2(u.y, f.z, f.w);
    } else {
      f = ((const float4*)W1)[(size_t)c*4 + q];
    }
    acc.x += wgt*f.x; acc.y += wgt*f.y; acc.z += wgt*f.z; acc.w += wgt*f.w;
  }
  ((float4*)C)[(size_t)psx*4 + q] = acc;
}

// h[s] = relu(bias1 + contiguous segment sum of C). Thread per (s, emb-quad).
__global__ void k_hsum(const int* start_s, const float* C, const void* bias1,
                       float* h, const int* flag){
  int bf = *flag;
  int id = blockIdx.x*256 + threadIdx.x;
  if(id >= NNODE*4) return;
  int s = id >> 2, q = id & 3;
  int e0 = start_s[s], e1 = start_s[s+1];
  float4 acc = {0.f,0.f,0.f,0.f};
  for(int e = e0; e < e1; e++){
    float4 c = ((const float4*)C)[(size_t)e*4 + q];
    acc.x += c.x; acc.y += c.y; acc.z += c.z; acc.w += c.w;
  }
  float4 o4;
  o4.x = fmaxf(acc.x + ldf(bias1, q*4+0, bf), 0.f);
  o4.y = fmaxf(acc.y + ldf(bias1, q*4+1, bf), 0.f);
  o4.z = fmaxf(acc.z + ldf(bias1, q*4+2, bf), 0.f);
  o4.w = fmaxf(acc.w + ldf(bias1, q*4+3, bf), 0.f);
  ((float4*)h)[(size_t)s*4 + q] = o4;
}

// E[r][s][:] (bf16, transposed) = sum_{edges of s} T2[p][r]*h[o];
// S2[s][r] = sum T2[p][r]. Cooperative rec load + shfl broadcast, 2x unroll.
// r=0 floods (fp32) -> floodE[64][16], floodS2[64].
__global__ __launch_bounds__(256) void k_E(const int* start_s, const int* rec_s,
    const float* T2, const float* h, unsigned* Ebf, float* S2,
    float* floodE, float* floodS2){
  __shared__ float lT2[NREL*RPD];
  __shared__ float sred[4][16];
  __shared__ float sred2[4];
  int tid = threadIdx.x;
  for(int i = tid; i < NREL*RPD; i += 256) lT2[i] = T2[i];
  __syncthreads();
  int wave = tid >> 6, lane = tid & 63;
  int r = lane >> 2, q = lane & 3;
  int s = blockIdx.x*4 + wave;
  float4 Ev = {0.f,0.f,0.f,0.f};
  float scs = 0.f;
  int e0 = start_s[s], e1 = start_s[s+1];
  const float4* h4 = (const float4*)h;
  for(int base = e0; base < e1; base += 64){
    int k = min(64, e1 - base);
    int rv = (lane < k) ? rec_s[base + lane] : 0;
    int i = 0;
    for(; i + 1 < k; i += 2){
      int w0 = __shfl(rv, i), w1 = __shfl(rv, i+1);
      float sc0 = lT2[(((unsigned)w0) >> 16)*RPD + r];
      float sc1 = lT2[(((unsigned)w1) >> 16)*RPD + r];
      float4 h0 = h4[(size_t)(w0 & 0xFFFF)*4 + q];
      float4 h1 = h4[(size_t)(w1 & 0xFFFF)*4 + q];
      Ev.x += sc0*h0.x; Ev.y += sc0*h0.y; Ev.z += sc0*h0.z; Ev.w += sc0*h0.w;
      Ev.x += sc1*h1.x; Ev.y += sc1*h1.y; Ev.z += sc1*h1.z; Ev.w += sc1*h1.w;
      scs += sc0 + sc1;
    }
    if(i < k){
      int w0 = __shfl(rv, i);
      float sc0 = lT2[(((unsigned)w0) >> 16)*RPD + r];
      float4 h0 = h4[(size_t)(w0 & 0xFFFF)*4 + q];
      Ev.x += sc0*h0.x; Ev.y += sc0*h0.y; Ev.z += sc0*h0.z; Ev.w += sc0*h0.w;
      scs += sc0;
    }
  }
  // bf16 pack: plane r, node s, elems q*4..q*4+3 -> 2 words at ((r*N+s)*8 + q*2)
  uint2 pk;
  pk.x = bfb(Ev.x) | (bfb(Ev.y) << 16);
  pk.y = bfb(Ev.z) | (bfb(Ev.w) << 16);
  *(uint2*)(Ebf + ((size_t)r*NNODE + s)*8 + q*2) = pk;
  if(q == 0) S2[s*RPD + r] = scs;
  if(r == 0){
    sred[wave][q*4+0] = Ev.x; sred[wave][q*4+1] = Ev.y;
    sred[wave][q*4+2] = Ev.z; sred[wave][q*4+3] = Ev.w;
    if(q == 0) sred2[wave] = scs;
  }
  __syncthreads();
  if(tid < 16){
    float v = sred[0][tid]+sred[1][tid]+sred[2][tid]+sred[3][tid];
    atomicAdd(&floodE[(blockIdx.x & 63)*16 + tid], v);
  }
  if(tid == 0)
    atomicAdd(&floodS2[blockIdx.x & 63], sred2[0]+sred2[1]+sred2[2]+sred2[3]);
}

// thread per output node: enumerate divisors, read bf16-transposed E (dense per
// r-plane), inline rowsum from S2, W2^T, bias, store.
__global__ __launch_bounds__(256) void k_logitsB(const unsigned* Ebf, const float* S2,
    const void* W2, const void* bias2, const float* floodS2, const float* floodE,
    void* out, const int* flag){
  __shared__ float lW2[15*EMB*NC];
  int bf = *flag;
  int tid = threadIdx.x;
  for(int i = tid; i < 15*EMB*NC; i += 256) lW2[i] = ldf(W2, i, bf);
  __syncthreads();
  int npi = blockIdx.x*256 + tid;
  if(npi >= NNODE) return;
  float acc[NC];
  #pragma unroll
  for(int c = 0; c < NC; c++) acc[c] = ldf(bias2, c, bf);
  #pragma unroll 1
  for(int rpi = 0; rpi < 15; rpi++){
    unsigned v = (unsigned)rpi*NNODE + (unsigned)npi;
    float4 ea = {0.f,0.f,0.f,0.f}, eb = ea, ec = ea, ed = ea;
    float rsum = 0.f;
    #pragma unroll
    for(int r = 1; r <= 15; r++){
      if(v % (unsigned)r == 0u){
        unsigned s = v / (unsigned)r;
        if(s < NNODE){
          rsum += S2[s*RPD + r];
          const uint4* Ep = ((const uint4*)Ebf) + ((size_t)r*NNODE + s)*2;
          uint4 A0 = Ep[0], B0 = Ep[1];
          float t0, t1;
          unpack2(A0.x, t0, t1); ea.x += t0; ea.y += t1;
          unpack2(A0.y, t0, t1); ea.z += t0; ea.w += t1;
          unpack2(A0.z, t0, t1); eb.x += t0; eb.y += t1;
          unpack2(A0.w, t0, t1); eb.z += t0; eb.w += t1;
          unpack2(B0.x, t0, t1); ec.x += t0; ec.y += t1;
          unpack2(B0.y, t0, t1); ec.z += t0; ec.w += t1;
          unpack2(B0.z, t0, t1); ed.x += t0; ed.y += t1;
          unpack2(B0.w, t0, t1); ed.z += t0; ed.w += t1;
        }
      }
    }
    if(rpi == 0 && npi == 0){
      for(int k = 0; k < 64; k++) rsum += floodS2[k];
      for(int k = 0; k < 64; k++){
        const float* fE = floodE + k*16;
        ea.x += fE[0];  ea.y += fE[1];  ea.z += fE[2];  ea.w += fE[3];
        eb.x += fE[4];  eb.y += fE[5];  eb.z += fE[6];  eb.w += fE[7];
        ec.x += fE[8];  ec.y += fE[9];  ec.z += fE[10]; ec.w += fE[11];
        ed.x += fE[12]; ed.y += fE[13]; ed.z += fE[14]; ed.w += fE[15];
      }
    }
    float inv = 1.f / fmaxf(rsum, EPSF);
    const float* w2 = lW2 + rpi*EMB*NC;
    #pragma unroll
    for(int c = 0; c < NC; c++){
      float g = w2[0*NC+c]*ea.x  + w2[1*NC+c]*ea.y  + w2[2*NC+c]*ea.z  + w2[3*NC+c]*ea.w
              + w2[4*NC+c]*eb.x  + w2[5*NC+c]*eb.y  + w2[6*NC+c]*eb.z  + w2[7*NC+c]*eb.w
              + w2[8*NC+c]*ec.x  + w2[9*NC+c]*ec.y  + w2[10*NC+c]*ec.z + w2[11*NC+c]*ec.w
              + w2[12*NC+c]*ed.x + w2[13*NC+c]*ed.y + w2[14*NC+c]*ed.z + w2[15*NC+c]*ed.w;
      acc[c] += inv * g;
    }
  }
  if(bf){
    #pragma unroll
    for(int c = 0; c < NC; c++) ((__hip_bfloat16*)out)[(size_t)npi*NC + c] = __float2bfloat16(acc[c]);
  } else {
    #pragma unroll
    for(int c = 0; c < NC; c++) ((float*)out)[(size_t)npi*NC + c] = acc[c];
  }
}

extern "C" void kernel_launch(void* const* d_in, const int* in_sizes, int n_in,
                              void* d_out, int out_size, void* d_ws, size_t ws_size,
                              hipStream_t stream){
  const void* nhots = d_in[0];
  const int* hrow = (const int*)d_in[1];   // hrow[t<NT] = s[t]
  const int* vcol = (const int*)d_in[4];   // vcol[t<NT] = o[t]
  const void* Wl1 = d_in[5];
  const void* bl1 = d_in[6];
  const void* Wl2 = d_in[7];
  const void* bl2 = d_in[8];
  const void* W1  = d_in[9];
  const void* bias1 = d_in[10];
  const void* W2  = d_in[11];
  const void* bias2 = d_in[12];

  float* ws = (float*)d_ws;
  int*   flag    = (int*)ws;                   // 16
  float* T1      = ws + 16;                    // 800
  float* T2      = T1 + 800;                   // 800
  int*   p       = (int*)(T2 + 800);           // 300000
  int*   rec_s   = p + 300000;                 // 300000
  int*   start_s = rec_s + 300000;             // 50004
  int*   start_o = start_s + 50004;            // 50004
  int*   cursor_s= start_o + 50004;            // 50000
  int*   cursor_o= cursor_s + 50000;           // 50000
  int*   bsum    = cursor_o + 50000;           // 128
  int*   cnt_s   = bsum + 128;                 // 50000  -- zero region start
  int*   cnt_o   = cnt_s + 50000;              // 50000
  float* floodSo = (float*)(cnt_o + 50000);    // 64
  float* floodS2 = floodSo + 64;               // 64
  float* floodE  = floodS2 + 64;               // 1024   -- zero end (101152 words)
  float* S2      = floodE + 1024;              // 800000
  float* h       = S2 + 800000;                // 800000
  float* A       = h + 800000;                 // overlay region
  float* S1      = A;                          // 800000
  float* icolsum = A + 800000;                 // 800000
  float* C       = A + 1600000;                // 4800000
  int*   rec_op  = (int*)(A + 6400000);        // 300000
  int*   rec_oo  = rec_op + 300000;            // 300000
  unsigned* Ebf  = (unsigned*)A;               // 6.4M words — S1/icolsum/C dead by k_E

  k_detect<<<1, 1024, 0, stream>>>((const unsigned*)nhots, flag);
  k_zero<<<396, 256, 0, stream>>>((float*)cnt_s, 101152L);
  k_tables<<<1, 128, 0, stream>>>(Wl1, bl1, Wl2, bl2, T1, T2, flag);

  const int nblk = (NTOT + 255) / 256;  // 1172
  k_argmax<<<nblk, 256, 0, stream>>>(nhots, hrow, vcol, p, cnt_s, cnt_o, flag);
  k_scanA<<<2*SG, 1024, 0, stream>>>(cnt_s, cnt_o, start_s, start_o, bsum);
  k_scanB<<<1, 128, 0, stream>>>(bsum, start_s, start_o);
  k_scanC<<<2*SG, 1024, 0, stream>>>(start_s, start_o, cursor_s, cursor_o, bsum);
  k_fill<<<nblk, 256, 0, stream>>>(hrow, vcol, p, cursor_s, cursor_o, rec_s, rec_op, rec_oo);
  k_S1<<<12500, 256, 0, stream>>>(start_o, rec_op, T1, S1, floodSo);
  k_icolsum<<<1024, 256, 0, stream>>>(S1, floodSo, icolsum);
  k_hC<<<(NTOT*4 + 255)/256, 256, 0, stream>>>(rec_op, rec_oo, T1, icolsum, W1, C, flag);
  k_hsum<<<(NNODE*4 + 255)/256, 256, 0, stream>>>(start_s, C, bias1, h, flag);
  k_E<<<12500, 256, 0, stream>>>(start_s, rec_s, T2, h, Ebf, S2, floodE, floodS2);
  k_logitsB<<<(NNODE + 255)/256, 256, 0, stream>>>(Ebf, S2, W2, bias2, floodS2, floodE, d_out, flag);
}

// Round 10
// 494.971 us; speedup vs baseline: 1.0254x; 1.0254x over previous
//
#include <hip/hip_runtime.h>
#include <hip/hip_bf16.h>
#include <stdint.h>

#define NTOT  300000
#define NNODE 50000
#define RPD   16
#define NREL  50
#define EMB   16
#define NC    10
#define EPSF  1e-6f
#define SG    49   // scan blocks per side: 49*1024 >= 50000

typedef const __hip_bfloat16* bf16p;

__device__ __forceinline__ float b2f(__hip_bfloat16 x){ return __bfloat162float(x); }

__device__ __forceinline__ void unpack2(unsigned u, float& a, float& b){
  a = __uint_as_float(u << 16);
  b = __uint_as_float(u & 0xffff0000u);
}

// fp32 -> bf16 bits, round-to-nearest-even
__device__ __forceinline__ unsigned bfb(float x){
  unsigned u = __float_as_uint(x);
  return (u + 0x7FFFu + ((u >> 16) & 1u)) >> 16;
}

__device__ __forceinline__ float ldf(const void* p, int i, int bf){
  return bf ? b2f(((bf16p)p)[i]) : ((const float*)p)[i];
}

// ---- dtype detection: fp32 one-hot rows contain ONLY words 0x0 / 0x3F800000.
__global__ void k_detect(const unsigned* nraw, int* flag){
  __shared__ int bad;
  if(threadIdx.x == 0) bad = 0;
  __syncthreads();
  for(int i = threadIdx.x; i < 4096; i += 1024){
    unsigned w = nraw[i];
    if(w != 0u && w != 0x3F800000u) bad = 1;
  }
  __syncthreads();
  if(threadIdx.x == 0) *flag = bad;   // 1 => bf16 mode, 0 => fp32 mode
}

__global__ void k_zero(float* p, long n){
  long i = (long)blockIdx.x*blockDim.x + threadIdx.x;
  long stride = (long)gridDim.x*blockDim.x;
  for(; i < n; i += stride) p[i] = 0.f;
}

// softmax tables: T1/T2[rel][r] = softmax_r(Wl[rel][r] + bl[r])
__global__ void k_tables(const void* Wl1, const void* bl1, const void* Wl2, const void* bl2,
                         float* T1, float* T2, const int* flag){
  int bf = *flag;
  int i = threadIdx.x;
  const void* W = nullptr; const void* bl = nullptr; float* T = nullptr; int row = -1;
  if(i < NREL){ W = Wl1; bl = bl1; T = T1; row = i; }
  else if(i >= 64 && i < 64 + NREL){ W = Wl2; bl = bl2; T = T2; row = i - 64; }
  if(row >= 0){
    float v[RPD]; float m = -1e30f;
    for(int r = 0; r < RPD; r++){
      v[r] = ldf(W, row*RPD + r, bf) + ldf(bl, r, bf);
      m = fmaxf(m, v[r]);
    }
    float s = 0.f;
    for(int r = 0; r < RPD; r++){ v[r] = __expf(v[r] - m); s += v[r]; }
    float inv = 1.f / s;
    for(int r = 0; r < RPD; r++) T[row*RPD + r] = v[r] * inv;
  }
}

// argmax relation per edge + degree histograms for both CSRs
__global__ __launch_bounds__(256) void k_argmax(const void* nhots, const int* srow, const int* ocol,
    int* p, int* cnt_s, int* cnt_o, const int* flag){
  int bf = *flag;
  int t = blockIdx.x*256 + threadIdx.x;
  if(t >= NTOT) return;
  int pt = 0; float best = -1e30f;
  if(bf){
    const unsigned* row = (const unsigned*)nhots + (size_t)t*(NREL/2);
    for(int k = 0; k < NREL/2; k++){
      float a, b; unpack2(row[k], a, b);
      if(a > best){ best = a; pt = 2*k;   }
      if(b > best){ best = b; pt = 2*k+1; }
    }
  } else {
    const uint2* row = (const uint2*)((const float*)nhots + (size_t)t*NREL);
    for(int k = 0; k < NREL/2; k++){
      uint2 u = row[k];
      float a = __uint_as_float(u.x), b = __uint_as_float(u.y);
      if(a > best){ best = a; pt = 2*k;   }
      if(b > best){ best = b; pt = 2*k+1; }
    }
  }
  p[t] = pt;
  atomicAdd(&cnt_s[srow[t]], 1);
  atomicAdd(&cnt_o[ocol[t]], 1);
}

// ---- 3-phase scan
__global__ __launch_bounds__(1024) void k_scanA(const int* cnt_s, const int* cnt_o,
    int* start_s, int* start_o, int* bsum){
  int G = gridDim.x >> 1;
  bool oside = blockIdx.x >= G;
  int b = oside ? blockIdx.x - G : blockIdx.x;
  const int* cnt = oside ? cnt_o : cnt_s;
  int* start = oside ? start_o : start_s;
  __shared__ int sh[1024];
  int tid = threadIdx.x;
  int idx = b*1024 + tid;
  int v = (idx < NNODE) ? cnt[idx] : 0;
  sh[tid] = v;
  __syncthreads();
  for(int off = 1; off < 1024; off <<= 1){
    int n = (tid >= off) ? sh[tid - off] : 0;
    __syncthreads();
    sh[tid] += n;
    __syncthreads();
  }
  if(idx < NNODE) start[idx] = sh[tid] - v;   // block-local exclusive
  if(tid == 1023) bsum[(oside ? G : 0) + b] = sh[1023];
}

__global__ void k_scanB(int* bsum, int* start_s, int* start_o){
  int tid = threadIdx.x;          // 128 = 2 waves; wave0 = s-side, wave1 = o-side
  bool oside = tid >= 64;
  int lane = tid & 63;
  int base = oside ? SG : 0;
  int v = (lane < SG) ? bsum[base + lane] : 0;
  int orig = v;
  for(int off = 1; off < 64; off <<= 1){
    int n = __shfl_up(v, off);
    if(lane >= off) v += n;
  }
  if(lane < SG) bsum[base + lane] = v - orig;  // exclusive block offset
  if(lane == 63){
    if(oside) start_o[NNODE] = v; else start_s[NNODE] = v;
  }
}

__global__ __launch_bounds__(1024) void k_scanC(int* start_s, int* start_o,
    int* cursor_s, int* cursor_o, const int* bsum){
  int G = gridDim.x >> 1;
  bool oside = blockIdx.x >= G;
  int b = oside ? blockIdx.x - G : blockIdx.x;
  int idx = b*1024 + threadIdx.x;
  if(idx >= NNODE) return;
  int ofs = bsum[(oside ? G : 0) + b];
  int* start  = oside ? start_o  : start_s;
  int* cursor = oside ? cursor_o : cursor_s;
  int v = start[idx] + ofs;
  start[idx] = v;
  cursor[idx] = v;
}

// fill both CSRs with PACKED edge records (SoA for the o-side):
//   rec_s[pos]   = o | p<<16    (o < 2^16, p < 64)
//   rec_op[posO] = pos_s | p<<19 (pos_s < 2^19),  rec_oo[posO] = o
__global__ void k_fill(const int* srow, const int* ocol, const int* p,
                       int* cursor_s, int* cursor_o, int* rec_s, int* rec_op, int* rec_oo){
  int t = blockIdx.x*256 + threadIdx.x;
  if(t >= NTOT) return;
  int s = srow[t], o = ocol[t], pt = p[t];
  int pos  = atomicAdd(&cursor_s[s], 1);
  int posO = atomicAdd(&cursor_o[o], 1);
  rec_s[pos] = o | (pt << 16);
  rec_op[posO] = pos | (pt << 19);
  rec_oo[posO] = o;
}

// S1[o][r] = sum_{edges of o} T1[p][r]. Wave per node; cooperative rec load +
// shfl broadcast => LDS-only inner loop. r=0 flood partials -> floodSo[64].
__global__ __launch_bounds__(256) void k_S1(const int* start_o, const int* rec_op,
    const float* T1, float* S1, float* floodSo){
  __shared__ float lT[NREL*RPD];
  __shared__ float w0[4];
  int tid = threadIdx.x;
  for(int i = tid; i < NREL*RPD; i += 256) lT[i] = T1[i];
  __syncthreads();
  int wave = tid >> 6, lane = tid & 63;
  int r = lane & 15;
  int node = blockIdx.x*4 + wave;
  float acc = 0.f;
  int e0 = start_o[node], e1 = start_o[node+1];
  for(int base = e0; base < e1; base += 64){
    int k = min(64, e1 - base);
    int rv = (lane < k) ? rec_op[base + lane] : 0;
    for(int i = 0; i < k; i++){
      int pt = ((unsigned)__shfl(rv, i)) >> 19;
      acc += lT[pt*RPD + r];
    }
  }
  if(lane < 16) S1[node*RPD + r] = acc;
  if(lane == 0) w0[wave] = acc;   // r==0 value
  __syncthreads();
  if(tid == 0)
    atomicAdd(&floodSo[blockIdx.x & 63], w0[0]+w0[1]+w0[2]+w0[3]);
}

// icolsum[v] = 1/max(eps, sum_{r=1..15, r|v, v/r<N} S1[v/r][r]); v==0 adds the r=0 flood.
__global__ __launch_bounds__(256) void k_icolsum(const float* S1, const float* floodSo, float* icolsum){
  int stride = gridDim.x*256;
  for(int v = blockIdx.x*256 + threadIdx.x; v < NNODE*RPD; v += stride){
    float acc = 0.f;
    #pragma unroll
    for(int r = 1; r <= 15; r++){
      if(v % (unsigned)r == 0u){
        int s = (unsigned)v / (unsigned)r;
        if(s < NNODE) acc += S1[s*RPD + r];
      }
    }
    if(v == 0){
      float f = 0.f;
      for(int k = 0; k < 64; k++) f += floodSo[k];
      acc += f;
    }
    icolsum[v] = 1.f / fmaxf(acc, EPSF);
  }
}

// layer1, edge x emb-quad parallel, fully coalesced record reads:
// C[psx][q] = sum_r T1[pt][r] * icolsum[o*r] * W1[o*r][q-quad]
__global__ __launch_bounds__(256) void k_hC(const int* rec_op, const int* rec_oo,
    const float* T1, const float* icolsum, const void* W1, float* C, const int* flag){
  __shared__ float lT1[NREL*RPD];
  int bf = *flag;
  int tid = threadIdx.x;
  for(int i = tid; i < NREL*RPD; i += 256) lT1[i] = T1[i];
  __syncthreads();
  int id = blockIdx.x*256 + tid;
  int e = id >> 2, q = id & 3;
  if(e >= NTOT) return;
  int w  = rec_op[e];
  int o  = rec_oo[e];
  int psx = w & 0x7FFFF;
  int pt  = ((unsigned)w) >> 19;
  const float* t1 = lT1 + pt*RPD;
  float4 acc = {0.f,0.f,0.f,0.f};
  #pragma unroll
  for(int r = 0; r < RPD; r++){
    int c = o * r;
    float wgt = t1[r] * icolsum[c];
    float4 f;
    if(bf){
      uint2 u = *((const uint2*)((const char*)W1 + (size_t)c*32) + q);
      unpack2(u.x, f.x, f.y); unpack2(u.y, f.z, f.w);
    } else {
      f = ((const float4*)W1)[(size_t)c*4 + q];
    }
    acc.x += wgt*f.x; acc.y += wgt*f.y; acc.z += wgt*f.z; acc.w += wgt*f.w;
  }
  ((float4*)C)[(size_t)psx*4 + q] = acc;
}

// h[s] = relu(bias1 + contiguous segment sum of C). Thread per (s, emb-quad).
__global__ void k_hsum(const int* start_s, const float* C, const void* bias1,
                       float* h, const int* flag){
  int bf = *flag;
  int id = blockIdx.x*256 + threadIdx.x;
  if(id >= NNODE*4) return;
  int s = id >> 2, q = id & 3;
  int e0 = start_s[s], e1 = start_s[s+1];
  float4 acc = {0.f,0.f,0.f,0.f};
  for(int e = e0; e < e1; e++){
    float4 c = ((const float4*)C)[(size_t)e*4 + q];
    acc.x += c.x; acc.y += c.y; acc.z += c.z; acc.w += c.w;
  }
  float4 o4;
  o4.x = fmaxf(acc.x + ldf(bias1, q*4+0, bf), 0.f);
  o4.y = fmaxf(acc.y + ldf(bias1, q*4+1, bf), 0.f);
  o4.z = fmaxf(acc.z + ldf(bias1, q*4+2, bf), 0.f);
  o4.w = fmaxf(acc.w + ldf(bias1, q*4+3, bf), 0.f);
  ((float4*)h)[(size_t)s*4 + q] = o4;
}

// E[r][s][:] (bf16, transposed) = sum_{edges of s} T2[p][r]*h[o];
// S2[s][r] = sum T2[p][r]. Cooperative rec load + shfl broadcast, 2x unroll.
// r=0 floods (fp32) -> floodE[64][16], floodS2[64].
__global__ __launch_bounds__(256) void k_E(const int* start_s, const int* rec_s,
    const float* T2, const float* h, unsigned* Ebf, float* S2,
    float* floodE, float* floodS2){
  __shared__ float lT2[NREL*RPD];
  __shared__ float sred[4][16];
  __shared__ float sred2[4];
  int tid = threadIdx.x;
  for(int i = tid; i < NREL*RPD; i += 256) lT2[i] = T2[i];
  __syncthreads();
  int wave = tid >> 6, lane = tid & 63;
  int r = lane >> 2, q = lane & 3;
  int s = blockIdx.x*4 + wave;
  float4 Ev = {0.f,0.f,0.f,0.f};
  float scs = 0.f;
  int e0 = start_s[s], e1 = start_s[s+1];
  const float4* h4 = (const float4*)h;
  for(int base = e0; base < e1; base += 64){
    int k = min(64, e1 - base);
    int rv = (lane < k) ? rec_s[base + lane] : 0;
    int i = 0;
    for(; i + 1 < k; i += 2){
      int w0 = __shfl(rv, i), w1 = __shfl(rv, i+1);
      float sc0 = lT2[(((unsigned)w0) >> 16)*RPD + r];
      float sc1 = lT2[(((unsigned)w1) >> 16)*RPD + r];
      float4 h0 = h4[(size_t)(w0 & 0xFFFF)*4 + q];
      float4 h1 = h4[(size_t)(w1 & 0xFFFF)*4 + q];
      Ev.x += sc0*h0.x; Ev.y += sc0*h0.y; Ev.z += sc0*h0.z; Ev.w += sc0*h0.w;
      Ev.x += sc1*h1.x; Ev.y += sc1*h1.y; Ev.z += sc1*h1.z; Ev.w += sc1*h1.w;
      scs += sc0 + sc1;
    }
    if(i < k){
      int w0 = __shfl(rv, i);
      float sc0 = lT2[(((unsigned)w0) >> 16)*RPD + r];
      float4 h0 = h4[(size_t)(w0 & 0xFFFF)*4 + q];
      Ev.x += sc0*h0.x; Ev.y += sc0*h0.y; Ev.z += sc0*h0.z; Ev.w += sc0*h0.w;
      scs += sc0;
    }
  }
  // bf16 pack: plane r, node s, elems q*4..q*4+3 -> 2 words at ((r*N+s)*8 + q*2)
  uint2 pk;
  pk.x = bfb(Ev.x) | (bfb(Ev.y) << 16);
  pk.y = bfb(Ev.z) | (bfb(Ev.w) << 16);
  *(uint2*)(Ebf + ((size_t)r*NNODE + s)*8 + q*2) = pk;
  if(q == 0) S2[s*RPD + r] = scs;
  if(r == 0){
    sred[wave][q*4+0] = Ev.x; sred[wave][q*4+1] = Ev.y;
    sred[wave][q*4+2] = Ev.z; sred[wave][q*4+3] = Ev.w;
    if(q == 0) sred2[wave] = scs;
  }
  __syncthreads();
  if(tid < 16){
    float v = sred[0][tid]+sred[1][tid]+sred[2][tid]+sred[3][tid];
    atomicAdd(&floodE[(blockIdx.x & 63)*16 + tid], v);
  }
  if(tid == 0)
    atomicAdd(&floodS2[blockIdx.x & 63], sred2[0]+sred2[1]+sred2[2]+sred2[3]);
}

// (npi, rpi)-parallel logits: block = 16 npi-groups x 16 lanes (lane = rpi, 0..14).
// Each lane does its rpi's divisor enumeration; 4-round shfl_xor reduces the
// 10 class partials within the 16-lane group; lane 0 adds bias and stores.
__global__ __launch_bounds__(256) void k_logitsB(const unsigned* Ebf, const float* S2,
    const void* W2, const void* bias2, const float* floodS2, const float* floodE,
    void* out, const int* flag){
  __shared__ float lW2[15*EMB*NC];
  int bf = *flag;
  int tid = threadIdx.x;
  for(int i = tid; i < 15*EMB*NC; i += 256) lW2[i] = ldf(W2, i, bf);
  __syncthreads();
  int grp = tid >> 4;           // npi-group within block
  int lane = tid & 15;          // rpi (15 == idle)
  int npi = blockIdx.x*16 + grp;
  float acc[NC];
  #pragma unroll
  for(int c = 0; c < NC; c++) acc[c] = 0.f;
  if(lane < 15){
    int rpi = lane;
    unsigned v = (unsigned)rpi*NNODE + (unsigned)npi;
    float4 ea = {0.f,0.f,0.f,0.f}, eb = ea, ec = ea, ed = ea;
    float rsum = 0.f;
    #pragma unroll
    for(int r = 1; r <= 15; r++){
      if(v % (unsigned)r == 0u){
        unsigned s = v / (unsigned)r;
        if(s < NNODE){
          rsum += S2[s*RPD + r];
          const uint4* Ep = ((const uint4*)Ebf) + ((size_t)r*NNODE + s)*2;
          uint4 A0 = Ep[0], B0 = Ep[1];
          float t0, t1;
          unpack2(A0.x, t0, t1); ea.x += t0; ea.y += t1;
          unpack2(A0.y, t0, t1); ea.z += t0; ea.w += t1;
          unpack2(A0.z, t0, t1); eb.x += t0; eb.y += t1;
          unpack2(A0.w, t0, t1); eb.z += t0; eb.w += t1;
          unpack2(B0.x, t0, t1); ec.x += t0; ec.y += t1;
          unpack2(B0.y, t0, t1); ec.z += t0; ec.w += t1;
          unpack2(B0.z, t0, t1); ed.x += t0; ed.y += t1;
          unpack2(B0.w, t0, t1); ed.z += t0; ed.w += t1;
        }
      }
    }
    if(npi == 0 && rpi == 0){   // r=0 flood contribution (v==0 row)
      for(int k = 0; k < 64; k++) rsum += floodS2[k];
      for(int k = 0; k < 64; k++){
        const float* fE = floodE + k*16;
        ea.x += fE[0];  ea.y += fE[1];  ea.z += fE[2];  ea.w += fE[3];
        eb.x += fE[4];  eb.y += fE[5];  eb.z += fE[6];  eb.w += fE[7];
        ec.x += fE[8];  ec.y += fE[9];  ec.z += fE[10]; ec.w += fE[11];
        ed.x += fE[12]; ed.y += fE[13]; ed.z += fE[14]; ed.w += fE[15];
      }
    }
    float inv = 1.f / fmaxf(rsum, EPSF);
    const float* w2 = lW2 + rpi*EMB*NC;
    #pragma unroll
    for(int c = 0; c < NC; c++){
      float g = w2[0*NC+c]*ea.x  + w2[1*NC+c]*ea.y  + w2[2*NC+c]*ea.z  + w2[3*NC+c]*ea.w
              + w2[4*NC+c]*eb.x  + w2[5*NC+c]*eb.y  + w2[6*NC+c]*eb.z  + w2[7*NC+c]*eb.w
              + w2[8*NC+c]*ec.x  + w2[9*NC+c]*ec.y  + w2[10*NC+c]*ec.z + w2[11*NC+c]*ec.w
              + w2[12*NC+c]*ed.x + w2[13*NC+c]*ed.y + w2[14*NC+c]*ed.z + w2[15*NC+c]*ed.w;
      acc[c] = inv * g;
    }
  }
  // reduce the 16-lane group (xor masks < 16 stay within the group)
  #pragma unroll
  for(int m = 1; m <= 8; m <<= 1){
    #pragma unroll
    for(int c = 0; c < NC; c++) acc[c] += __shfl_xor(acc[c], m);
  }
  if(lane == 0){
    if(bf){
      #pragma unroll
      for(int c = 0; c < NC; c++)
        ((__hip_bfloat16*)out)[(size_t)npi*NC + c] = __float2bfloat16(acc[c] + ldf(bias2, c, 1));
    } else {
      #pragma unroll
      for(int c = 0; c < NC; c++)
        ((float*)out)[(size_t)npi*NC + c] = acc[c] + ldf(bias2, c, 0);
    }
  }
}

extern "C" void kernel_launch(void* const* d_in, const int* in_sizes, int n_in,
                              void* d_out, int out_size, void* d_ws, size_t ws_size,
                              hipStream_t stream){
  const void* nhots = d_in[0];
  const int* hrow = (const int*)d_in[1];   // hrow[t<NT] = s[t]
  const int* vcol = (const int*)d_in[4];   // vcol[t<NT] = o[t]
  const void* Wl1 = d_in[5];
  const void* bl1 = d_in[6];
  const void* Wl2 = d_in[7];
  const void* bl2 = d_in[8];
  const void* W1  = d_in[9];
  const void* bias1 = d_in[10];
  const void* W2  = d_in[11];
  const void* bias2 = d_in[12];

  float* ws = (float*)d_ws;
  int*   flag    = (int*)ws;                   // 16
  float* T1      = ws + 16;                    // 800
  float* T2      = T1 + 800;                   // 800
  int*   p       = (int*)(T2 + 800);           // 300000
  int*   rec_s   = p + 300000;                 // 300000
  int*   start_s = rec_s + 300000;             // 50004
  int*   start_o = start_s + 50004;            // 50004
  int*   cursor_s= start_o + 50004;            // 50000
  int*   cursor_o= cursor_s + 50000;           // 50000
  int*   bsum    = cursor_o + 50000;           // 128
  int*   cnt_s   = bsum + 128;                 // 50000  -- zero region start
  int*   cnt_o   = cnt_s + 50000;              // 50000
  float* floodSo = (float*)(cnt_o + 50000);    // 64
  float* floodS2 = floodSo + 64;               // 64
  float* floodE  = floodS2 + 64;               // 1024   -- zero end (101152 words)
  float* S2      = floodE + 1024;              // 800000
  float* h       = S2 + 800000;                // 800000
  float* A       = h + 800000;                 // overlay region
  float* S1      = A;                          // 800000
  float* icolsum = A + 800000;                 // 800000
  float* C       = A + 1600000;                // 4800000
  int*   rec_op  = (int*)(A + 6400000);        // 300000
  int*   rec_oo  = rec_op + 300000;            // 300000
  unsigned* Ebf  = (unsigned*)A;               // 6.4M words — S1/icolsum/C dead by k_E

  k_detect<<<1, 1024, 0, stream>>>((const unsigned*)nhots, flag);
  k_zero<<<396, 256, 0, stream>>>((float*)cnt_s, 101152L);
  k_tables<<<1, 128, 0, stream>>>(Wl1, bl1, Wl2, bl2, T1, T2, flag);

  const int nblk = (NTOT + 255) / 256;  // 1172
  k_argmax<<<nblk, 256, 0, stream>>>(nhots, hrow, vcol, p, cnt_s, cnt_o, flag);
  k_scanA<<<2*SG, 1024, 0, stream>>>(cnt_s, cnt_o, start_s, start_o, bsum);
  k_scanB<<<1, 128, 0, stream>>>(bsum, start_s, start_o);
  k_scanC<<<2*SG, 1024, 0, stream>>>(start_s, start_o, cursor_s, cursor_o, bsum);
  k_fill<<<nblk, 256, 0, stream>>>(hrow, vcol, p, cursor_s, cursor_o, rec_s, rec_op, rec_oo);
  k_S1<<<12500, 256, 0, stream>>>(start_o, rec_op, T1, S1, floodSo);
  k_icolsum<<<1024, 256, 0, stream>>>(S1, floodSo, icolsum);
  k_hC<<<(NTOT*4 + 255)/256, 256, 0, stream>>>(rec_op, rec_oo, T1, icolsum, W1, C, flag);
  k_hsum<<<(NNODE*4 + 255)/256, 256, 0, stream>>>(start_s, C, bias1, h, flag);
  k_E<<<12500, 256, 0, stream>>>(start_s, rec_s, T2, h, Ebf, S2, floodE, floodS2);
  k_logitsB<<<NNODE/16, 256, 0, stream>>>(Ebf, S2, W2, bias2, floodS2, floodE, d_out, flag);
}